// Round 10
// baseline (547.278 us; speedup 1.0000x reference)
//
#include <hip/hip_runtime.h>

// out = segment_sum( coef(e_feat) * (emb[src] ⊙ weight), dst, N )
// coef(v) = sw[0] + (v==0)*sw[1] + (v==2)*sw[2] + (v==4)*sw[3] + (v==6)*sw[4]
//
// R10: LDS-staged coarse-bucket binning.
//   R9 showed scatter WRITE = #stores × 64B (write-through of isolated random
//   stores). Fix: block-local radix pass sorts 4096 edges by 256-node bucket
//   in LDS, then writes contiguous per-bucket runs -> coalesced.
//   Records are 4B: src(17) | dst_low(8)<<17 | ef(3)<<25.
//   k_accum: one block per bucket, 64KB LDS slab, LDS-atomic accumulate,
//   coalesced row writes (covers every node -> no d_out memset needed).

#define DIM 64
#define LOGBUK 8
#define NPB 256                 // nodes per bucket
#define CAP 6144                // record slots per bucket (avg load 2560)
#define CHUNK 4096              // edges per bin block
#define OVF_CAP 8192

// ---------------- pass 1: LDS-staged binning ----------------
__global__ __launch_bounds__(512) void k_bin(
    const int* __restrict__ e_feat, const int* __restrict__ src_idx,
    const int* __restrict__ dst_idx,
    int* __restrict__ cursor, int* __restrict__ ovf_cnt, int4* __restrict__ ovf,
    unsigned int* __restrict__ recs, int E, int nbuk)
{
    __shared__ int hist[512];
    __shared__ int ss[512];                  // inclusive scan of hist
    __shared__ int adjs[512];                // global_base - local_start per bucket
    __shared__ unsigned int stage_rec[CHUNK];
    __shared__ unsigned short stage_b[CHUNK];

    const int t = threadIdx.x;
    const int base = blockIdx.x * CHUNK;
    int n = E - base; if (n > CHUNK) n = CHUNK;

    hist[t] = 0;
    __syncthreads();

    unsigned int rec[8]; int bk[8]; int lr[8];
    #pragma unroll
    for (int k = 0; k < 8; ++k) {
        int i = t + k * 512;
        if (i < n) {
            int j = base + i;
            int d = dst_idx[j];
            int s = src_idx[j];
            int f = e_feat[j];
            bk[k]  = d >> LOGBUK;
            rec[k] = (unsigned)s | ((unsigned)(d & (NPB - 1)) << 17)
                                 | ((unsigned)f << 25);
            lr[k]  = atomicAdd(&hist[bk[k]], 1);
        } else bk[k] = -1;
    }
    __syncthreads();

    // inclusive Hillis-Steele scan of hist -> ss (512 entries, 512 threads)
    ss[t] = hist[t];
    __syncthreads();
    for (int off = 1; off < 512; off <<= 1) {
        int tv = (t >= off) ? ss[t - off] : 0;
        __syncthreads();
        ss[t] += tv;
        __syncthreads();
    }
    // exclusive start of bucket b = ss[b] - hist[b]

    #pragma unroll
    for (int k = 0; k < 8; ++k) {
        if (bk[k] >= 0) {
            int pos = ss[bk[k]] - hist[bk[k]] + lr[k];
            stage_rec[pos] = rec[k];
            stage_b[pos]   = (unsigned short)bk[k];
        }
    }
    // one cursor bump per (block,bucket)
    if (t < nbuk) {
        int cnt = hist[t];
        if (cnt > 0) {
            int b0 = atomicAdd(&cursor[t], cnt);
            adjs[t] = b0 - (ss[t] - cnt);
        }
    }
    __syncthreads();

    // coalesced copy: consecutive i -> consecutive positions within runs
    for (int i = t; i < n; i += 512) {
        int b = stage_b[i];
        int dp = adjs[b] + i;
        unsigned int r = stage_rec[i];
        if (dp < CAP) {
            recs[(size_t)b * CAP + dp] = r;
        } else {
            int oi = atomicAdd(ovf_cnt, 1);
            if (oi < OVF_CAP) {
                int s  = r & 0x1FFFF;
                int dl = (r >> 17) & 0xFF;
                int f  = r >> 25;
                ovf[oi] = make_int4((b << LOGBUK) | dl, s, f, 0);
            }
        }
    }
}

// ---------------- pass 2: bucket-slab accumulate ----------------
__global__ __launch_bounds__(512) void k_accum(
    const float* __restrict__ emb, const float* __restrict__ weight,
    const float* __restrict__ sw,
    const int* __restrict__ cursor, const unsigned int* __restrict__ recs,
    float* __restrict__ out, int N)
{
    __shared__ float slab[NPB * DIM];        // 64 KB
    const int t    = threadIdx.x;
    const int b    = blockIdx.x;
    const int lane = t & 63;
    const int wv   = t >> 6;                 // 0..7

    for (int i = t; i < NPB * DIM; i += 512) slab[i] = 0.0f;

    float ctab[8];
    {
        float s0 = sw[0], s1 = sw[1], s2 = sw[2], s3 = sw[3], s4 = sw[4];
        #pragma unroll
        for (int f = 0; f < 8; ++f) {
            float c = s0;
            c += (f == 0) ? s1 : 0.0f;
            c += (f == 2) ? s2 : 0.0f;
            c += (f == 4) ? s3 : 0.0f;
            c += (f == 6) ? s4 : 0.0f;
            ctab[f] = c;
        }
    }
    int cnt = cursor[b]; if (cnt > CAP) cnt = CAP;
    const unsigned int* rp = recs + (size_t)b * CAP;
    __syncthreads();

    for (int basei = wv * 64; basei < cnt; basei += 512) {
        int nch = cnt - basei; if (nch > 64) nch = 64;
        unsigned int r = 0;
        if (lane < nch) r = rp[basei + lane];
        int j = 0;
        for (; j + 3 < nch; j += 4) {
            unsigned int r0 = __shfl(r, j    ), r1 = __shfl(r, j + 1);
            unsigned int r2 = __shfl(r, j + 2), r3 = __shfl(r, j + 3);
            float v0 = emb[(size_t)(r0 & 0x1FFFF) * DIM + lane];
            float v1 = emb[(size_t)(r1 & 0x1FFFF) * DIM + lane];
            float v2 = emb[(size_t)(r2 & 0x1FFFF) * DIM + lane];
            float v3 = emb[(size_t)(r3 & 0x1FFFF) * DIM + lane];
            atomicAdd(&slab[((r0 >> 17) & 0xFF) * DIM + lane], ctab[r0 >> 25] * v0);
            atomicAdd(&slab[((r1 >> 17) & 0xFF) * DIM + lane], ctab[r1 >> 25] * v1);
            atomicAdd(&slab[((r2 >> 17) & 0xFF) * DIM + lane], ctab[r2 >> 25] * v2);
            atomicAdd(&slab[((r3 >> 17) & 0xFF) * DIM + lane], ctab[r3 >> 25] * v3);
        }
        for (; j < nch; ++j) {
            unsigned int rj = __shfl(r, j);
            float v = emb[(size_t)(rj & 0x1FFFF) * DIM + lane];
            atomicAdd(&slab[((rj >> 17) & 0xFF) * DIM + lane], ctab[rj >> 25] * v);
        }
    }
    __syncthreads();

    const float wl = weight[lane];
    const int node0 = b << LOGBUK;
    for (int row = wv; row < NPB; row += 8) {
        int node = node0 + row;
        if (node < N)
            out[(size_t)node * DIM + lane] = slab[row * DIM + lane] * wl;
    }
}

// ---------------- pass 3: overflow fixup (normally zero work) ----------------
__global__ __launch_bounds__(64) void k_overflow(
    const int* __restrict__ ovf_cnt, const int4* __restrict__ ovf,
    const float* __restrict__ emb, const float* __restrict__ weight,
    const float* __restrict__ sw, float* __restrict__ out)
{
    int m = *ovf_cnt; if (m > OVF_CAP) m = OVF_CAP;
    int lane = threadIdx.x;
    float s0 = sw[0], s1 = sw[1], s2 = sw[2], s3 = sw[3], s4 = sw[4];
    for (int i = blockIdx.x; i < m; i += gridDim.x) {
        int4 rec = ovf[i];
        int f = rec.z;
        float c = s0;
        c += (f == 0) ? s1 : 0.0f;
        c += (f == 2) ? s2 : 0.0f;
        c += (f == 4) ? s3 : 0.0f;
        c += (f == 6) ? s4 : 0.0f;
        float v = emb[(size_t)rec.y * DIM + lane] * weight[lane] * c;
        atomicAdd(&out[(size_t)rec.x * DIM + lane], v);
    }
}

// ---------------- fallback (tiny ws): round-1 atomic kernel ----------------
__global__ __launch_bounds__(256) void edge_scatter_kernel(
    const float* __restrict__ emb, const int* __restrict__ e_feat,
    const int* __restrict__ src_idx, const int* __restrict__ dst_idx,
    const float* __restrict__ weight, const float* __restrict__ sw,
    float* __restrict__ out, int n_edges) {
    int tid = blockIdx.x * blockDim.x + threadIdx.x;
    int edge = tid >> 4;
    int quad = tid & 15;
    if (edge >= n_edges) return;
    int ef = e_feat[edge];
    float coef = sw[0];
    coef += (ef == 0) ? sw[1] : 0.0f;
    coef += (ef == 2) ? sw[2] : 0.0f;
    coef += (ef == 4) ? sw[3] : 0.0f;
    coef += (ef == 6) ? sw[4] : 0.0f;
    int src = src_idx[edge], dst = dst_idx[edge];
    const float4 ev = *reinterpret_cast<const float4*>(emb + (size_t)src * DIM + quad * 4);
    const float4 wv = *reinterpret_cast<const float4*>(weight + quad * 4);
    float* op = out + (size_t)dst * DIM + quad * 4;
    atomicAdd(op + 0, ev.x * wv.x * coef);
    atomicAdd(op + 1, ev.y * wv.y * coef);
    atomicAdd(op + 2, ev.z * wv.z * coef);
    atomicAdd(op + 3, ev.w * wv.w * coef);
}

extern "C" void kernel_launch(void* const* d_in, const int* in_sizes, int n_in,
                              void* d_out, int out_size, void* d_ws, size_t ws_size,
                              hipStream_t stream) {
    const float* emb     = (const float*)d_in[0];
    const int*   e_feat  = (const int*)d_in[1];
    const int*   src_idx = (const int*)d_in[2];
    const int*   dst_idx = (const int*)d_in[3];
    const float* weight  = (const float*)d_in[4];
    const float* sw      = (const float*)d_in[5];
    float* out = (float*)d_out;

    const int E = in_sizes[1];
    const int N = in_sizes[0] / DIM;
    const int nbuk = (N + NPB - 1) / NPB;    // 391 for N=100000

    // ws layout: cursor[nbuk] | ovf_cnt | pad | ovf[OVF_CAP] int4 | recs[nbuk*CAP] u32
    size_t off_cursor = 0;
    size_t off_ovfcnt = off_cursor + (size_t)nbuk * 4;
    size_t off_ovf    = (off_ovfcnt + 4 + 15) & ~(size_t)15;
    size_t off_recs   = (off_ovf + (size_t)OVF_CAP * 16 + 15) & ~(size_t)15;
    size_t needed     = off_recs + (size_t)nbuk * CAP * 4;

    if (nbuk > 512 || ws_size < needed) {
        hipMemsetAsync(d_out, 0, (size_t)out_size * sizeof(float), stream);
        int total = E * 16, block = 256;
        edge_scatter_kernel<<<(total + block - 1) / block, block, 0, stream>>>(
            emb, e_feat, src_idx, dst_idx, weight, sw, out, E);
        return;
    }

    char* ws = (char*)d_ws;
    int*          cursor  = (int*)(ws + off_cursor);
    int*          ovf_cnt = (int*)(ws + off_ovfcnt);
    int4*         ovf     = (int4*)(ws + off_ovf);
    unsigned int* recs    = (unsigned int*)(ws + off_recs);

    // zero cursors + overflow counter (contiguous)
    hipMemsetAsync(cursor, 0, off_ovfcnt + 16 - off_cursor, stream);

    k_bin<<<(E + CHUNK - 1) / CHUNK, 512, 0, stream>>>(
        e_feat, src_idx, dst_idx, cursor, ovf_cnt, ovf, recs, E, nbuk);

    k_accum<<<nbuk, 512, 0, stream>>>(emb, weight, sw, cursor, recs, out, N);

    k_overflow<<<64, 64, 0, stream>>>(ovf_cnt, ovf, emb, weight, sw, out);
}

// Round 11
// 538.123 us; speedup vs baseline: 1.0170x; 1.0170x over previous
//
#include <hip/hip_runtime.h>

// out = segment_sum( coef(e_feat) * (emb[src] ⊙ weight), dst, N )
// coef(v) = sw[0] + (v==0)*sw[1] + (v==2)*sw[2] + (v==4)*sw[3] + (v==6)*sw[4]
//
// R11: two-phase bucket binning, geometry fixed vs R10.
//   k_bin:   245 blocks stage CHUNK=4096 edges in LDS, group by 128-node
//            bucket (nbuk=782), write contiguous runs -> few 64B lines.
//   k_accum: one block per bucket, 32KB slab (4 blocks/CU = full thread
//            occupancy), LDS-atomic accumulate, coalesced row writes.
//   Record (u32): src(17) | dst_low(7)<<17 | ef(3)<<24.

#define DIM 64
#define LOGB 7
#define NPB 128                 // nodes per bucket
#define NBUK_MAX 1024
#define CAP 2048                // record slots per bucket (avg load ~1280)
#define CHUNK 4096              // edges per bin block
#define OVF_CAP 8192

// ---------------- pass 1: LDS-staged binning ----------------
__global__ __launch_bounds__(512) void k_bin(
    const int* __restrict__ e_feat, const int* __restrict__ src_idx,
    const int* __restrict__ dst_idx,
    int* __restrict__ cursor, int* __restrict__ ovf_cnt, int4* __restrict__ ovf,
    unsigned int* __restrict__ recs, int E, int nbuk)
{
    __shared__ int hist[NBUK_MAX];
    __shared__ int start[NBUK_MAX];
    __shared__ int adjs[NBUK_MAX];
    __shared__ int partial[512];
    __shared__ unsigned int stage_rec[CHUNK];
    __shared__ unsigned short stage_b[CHUNK];

    const int t = threadIdx.x;
    const int base = blockIdx.x * CHUNK;
    int n = E - base; if (n > CHUNK) n = CHUNK;

    hist[t] = 0; hist[t + 512] = 0;
    __syncthreads();

    unsigned int rec[8]; int bk[8]; int lr[8];
    #pragma unroll
    for (int k = 0; k < 8; ++k) {
        int i = t + k * 512;                 // strided -> coalesced loads
        if (i < n) {
            int j = base + i;
            int d = dst_idx[j];
            int s = src_idx[j];
            int f = e_feat[j];
            bk[k]  = d >> LOGB;
            rec[k] = (unsigned)s | ((unsigned)(d & (NPB - 1)) << 17)
                                 | ((unsigned)f << 24);
            lr[k]  = atomicAdd(&hist[bk[k]], 1);
        } else bk[k] = -1;
    }
    __syncthreads();

    // exclusive scan of hist[0..1024) -> start (2 buckets per thread)
    int a  = hist[2 * t];
    int b2 = hist[2 * t + 1];
    partial[t] = a + b2;
    __syncthreads();
    for (int off = 1; off < 512; off <<= 1) {
        int v = (t >= off) ? partial[t - off] : 0;
        __syncthreads();
        partial[t] += v;
        __syncthreads();
    }
    int pbase = partial[t] - (a + b2);       // exclusive
    start[2 * t]     = pbase;
    start[2 * t + 1] = pbase + a;
    __syncthreads();

    // stage records grouped by bucket
    #pragma unroll
    for (int k = 0; k < 8; ++k) {
        if (bk[k] >= 0) {
            int pos = start[bk[k]] + lr[k];
            stage_rec[pos] = rec[k];
            stage_b[pos]   = (unsigned short)bk[k];
        }
    }
    // one cursor bump per (block,bucket)
    for (int b = t; b < nbuk; b += 512) {
        int c = hist[b];
        if (c > 0) {
            int g0 = atomicAdd(&cursor[b], c);
            adjs[b] = g0 - start[b];
        }
    }
    __syncthreads();

    // copy: consecutive i -> consecutive global positions within runs
    for (int i = t; i < n; i += 512) {
        int b  = stage_b[i];
        int dp = adjs[b] + i;
        unsigned int r = stage_rec[i];
        if (dp < CAP) {
            recs[(size_t)b * CAP + dp] = r;
        } else {
            int oi = atomicAdd(ovf_cnt, 1);
            if (oi < OVF_CAP) {
                int s  = r & 0x1FFFF;
                int dl = (r >> 17) & (NPB - 1);
                int f  = (r >> 24) & 7;
                ovf[oi] = make_int4((b << LOGB) | dl, s, f, 0);
            }
        }
    }
}

// ---------------- pass 2: bucket-slab accumulate ----------------
__global__ __launch_bounds__(512) void k_accum(
    const float* __restrict__ emb, const float* __restrict__ weight,
    const float* __restrict__ sw,
    const int* __restrict__ cursor, const unsigned int* __restrict__ recs,
    float* __restrict__ out, int N)
{
    __shared__ float slab[NPB * DIM];        // 32 KB -> 4 blocks/CU
    const int t    = threadIdx.x;
    const int b    = blockIdx.x;
    const int lane = t & 63;
    const int wv   = t >> 6;                 // 0..7

    for (int i = t; i < NPB * DIM; i += 512) slab[i] = 0.0f;

    float ctab[8];
    {
        float s0 = sw[0], s1 = sw[1], s2 = sw[2], s3 = sw[3], s4 = sw[4];
        #pragma unroll
        for (int f = 0; f < 8; ++f) {
            float c = s0;
            c += (f == 0) ? s1 : 0.0f;
            c += (f == 2) ? s2 : 0.0f;
            c += (f == 4) ? s3 : 0.0f;
            c += (f == 6) ? s4 : 0.0f;
            ctab[f] = c;
        }
    }
    int cnt = cursor[b]; if (cnt > CAP) cnt = CAP;
    const unsigned int* rp = recs + (size_t)b * CAP;
    __syncthreads();

    for (int basei = wv * 64; basei < cnt; basei += 512) {
        int nch = cnt - basei; if (nch > 64) nch = 64;
        unsigned int r = 0;
        if (lane < nch) r = rp[basei + lane];
        int j = 0;
        for (; j + 3 < nch; j += 4) {
            unsigned int r0 = __shfl(r, j    ), r1 = __shfl(r, j + 1);
            unsigned int r2 = __shfl(r, j + 2), r3 = __shfl(r, j + 3);
            float v0 = emb[(size_t)(r0 & 0x1FFFF) * DIM + lane];
            float v1 = emb[(size_t)(r1 & 0x1FFFF) * DIM + lane];
            float v2 = emb[(size_t)(r2 & 0x1FFFF) * DIM + lane];
            float v3 = emb[(size_t)(r3 & 0x1FFFF) * DIM + lane];
            atomicAdd(&slab[((r0 >> 17) & (NPB - 1)) * DIM + lane], ctab[(r0 >> 24) & 7] * v0);
            atomicAdd(&slab[((r1 >> 17) & (NPB - 1)) * DIM + lane], ctab[(r1 >> 24) & 7] * v1);
            atomicAdd(&slab[((r2 >> 17) & (NPB - 1)) * DIM + lane], ctab[(r2 >> 24) & 7] * v2);
            atomicAdd(&slab[((r3 >> 17) & (NPB - 1)) * DIM + lane], ctab[(r3 >> 24) & 7] * v3);
        }
        for (; j < nch; ++j) {
            unsigned int rj = __shfl(r, j);
            float v = emb[(size_t)(rj & 0x1FFFF) * DIM + lane];
            atomicAdd(&slab[((rj >> 17) & (NPB - 1)) * DIM + lane], ctab[(rj >> 24) & 7] * v);
        }
    }
    __syncthreads();

    const float wl = weight[lane];
    const int node0 = b << LOGB;
    for (int row = wv; row < NPB; row += 8) {
        int node = node0 + row;
        if (node < N)
            out[(size_t)node * DIM + lane] = slab[row * DIM + lane] * wl;
    }
}

// ---------------- pass 3: overflow fixup (normally zero work) ----------------
__global__ __launch_bounds__(64) void k_overflow(
    const int* __restrict__ ovf_cnt, const int4* __restrict__ ovf,
    const float* __restrict__ emb, const float* __restrict__ weight,
    const float* __restrict__ sw, float* __restrict__ out)
{
    int m = *ovf_cnt; if (m > OVF_CAP) m = OVF_CAP;
    int lane = threadIdx.x;
    float s0 = sw[0], s1 = sw[1], s2 = sw[2], s3 = sw[3], s4 = sw[4];
    for (int i = blockIdx.x; i < m; i += gridDim.x) {
        int4 rec = ovf[i];
        int f = rec.z;
        float c = s0;
        c += (f == 0) ? s1 : 0.0f;
        c += (f == 2) ? s2 : 0.0f;
        c += (f == 4) ? s3 : 0.0f;
        c += (f == 6) ? s4 : 0.0f;
        float v = emb[(size_t)rec.y * DIM + lane] * weight[lane] * c;
        atomicAdd(&out[(size_t)rec.x * DIM + lane], v);
    }
}

// ---------------- fallback (tiny ws): round-1 atomic kernel ----------------
__global__ __launch_bounds__(256) void edge_scatter_kernel(
    const float* __restrict__ emb, const int* __restrict__ e_feat,
    const int* __restrict__ src_idx, const int* __restrict__ dst_idx,
    const float* __restrict__ weight, const float* __restrict__ sw,
    float* __restrict__ out, int n_edges) {
    int tid = blockIdx.x * blockDim.x + threadIdx.x;
    int edge = tid >> 4;
    int quad = tid & 15;
    if (edge >= n_edges) return;
    int ef = e_feat[edge];
    float coef = sw[0];
    coef += (ef == 0) ? sw[1] : 0.0f;
    coef += (ef == 2) ? sw[2] : 0.0f;
    coef += (ef == 4) ? sw[3] : 0.0f;
    coef += (ef == 6) ? sw[4] : 0.0f;
    int src = src_idx[edge], dst = dst_idx[edge];
    const float4 ev = *reinterpret_cast<const float4*>(emb + (size_t)src * DIM + quad * 4);
    const float4 wv = *reinterpret_cast<const float4*>(weight + quad * 4);
    float* op = out + (size_t)dst * DIM + quad * 4;
    atomicAdd(op + 0, ev.x * wv.x * coef);
    atomicAdd(op + 1, ev.y * wv.y * coef);
    atomicAdd(op + 2, ev.z * wv.z * coef);
    atomicAdd(op + 3, ev.w * wv.w * coef);
}

extern "C" void kernel_launch(void* const* d_in, const int* in_sizes, int n_in,
                              void* d_out, int out_size, void* d_ws, size_t ws_size,
                              hipStream_t stream) {
    const float* emb     = (const float*)d_in[0];
    const int*   e_feat  = (const int*)d_in[1];
    const int*   src_idx = (const int*)d_in[2];
    const int*   dst_idx = (const int*)d_in[3];
    const float* weight  = (const float*)d_in[4];
    const float* sw      = (const float*)d_in[5];
    float* out = (float*)d_out;

    const int E = in_sizes[1];
    const int N = in_sizes[0] / DIM;
    const int nbuk = (N + NPB - 1) / NPB;    // 782 for N=100000

    // ws layout: cursor[nbuk] | ovf_cnt | pad | ovf[OVF_CAP] int4 | recs[nbuk*CAP] u32
    size_t off_cursor = 0;
    size_t off_ovfcnt = off_cursor + (size_t)nbuk * 4;
    size_t off_ovf    = (off_ovfcnt + 4 + 15) & ~(size_t)15;
    size_t off_recs   = (off_ovf + (size_t)OVF_CAP * 16 + 15) & ~(size_t)15;
    size_t needed     = off_recs + (size_t)nbuk * CAP * 4;

    if (nbuk > NBUK_MAX || ws_size < needed) {
        hipMemsetAsync(d_out, 0, (size_t)out_size * sizeof(float), stream);
        int total = E * 16, block = 256;
        edge_scatter_kernel<<<(total + block - 1) / block, block, 0, stream>>>(
            emb, e_feat, src_idx, dst_idx, weight, sw, out, E);
        return;
    }

    char* ws = (char*)d_ws;
    int*          cursor  = (int*)(ws + off_cursor);
    int*          ovf_cnt = (int*)(ws + off_ovfcnt);
    int4*         ovf     = (int4*)(ws + off_ovf);
    unsigned int* recs    = (unsigned int*)(ws + off_recs);

    // zero cursors + overflow counter (contiguous)
    hipMemsetAsync(cursor, 0, off_ovfcnt + 16 - off_cursor, stream);

    k_bin<<<(E + CHUNK - 1) / CHUNK, 512, 0, stream>>>(
        e_feat, src_idx, dst_idx, cursor, ovf_cnt, ovf, recs, E, nbuk);

    k_accum<<<nbuk, 512, 0, stream>>>(emb, weight, sw, cursor, recs, out, N);

    k_overflow<<<64, 64, 0, stream>>>(ovf_cnt, ovf, emb, weight, sw, out);
}

// Round 12
// 158.427 us; speedup vs baseline: 3.4545x; 3.3967x over previous
//
#include <hip/hip_runtime.h>

// out = segment_sum( coef(e_feat) * (emb[src] ⊙ weight), dst, N )
// coef(v) = sw[0] + (v==0)*sw[1] + (v==2)*sw[2] + (v==4)*sw[3] + (v==6)*sw[4]
//
// R12: two-pass radix by dst, then wave-per-node register gather.
//   A k_bin:     LDS-stage 4096 edges, group by 128-node bucket, write
//                contiguous runs (coalesced; ~16MB vs 63MB write-through).
//   B k_regroup: block per bucket; LDS-sort records by node; write
//                node-grouped int2{src,coef} + meta{start,cnt} (coalesced).
//   C k_gather:  R4-proven wave-per-node, 8 accumulators, one row write.
//   Slab-accumulate abandoned (R10/R11: TLP-starved on latency-bound gathers).

#define DIM 64
#define LOGB 7
#define NPB 128                 // nodes per bucket
#define NBUK_MAX 1024
#define CAP 2048                // record slots per bucket (avg load ~1280)
#define CHUNK 4096              // edges per bin block
#define OVF_CAP 8192

// ---------------- pass A: LDS-staged binning (from R11, proven correct) ----------------
__global__ __launch_bounds__(512) void k_bin(
    const int* __restrict__ e_feat, const int* __restrict__ src_idx,
    const int* __restrict__ dst_idx,
    int* __restrict__ cursor, int* __restrict__ ovf_cnt, int4* __restrict__ ovf,
    unsigned int* __restrict__ recs, int E, int nbuk)
{
    __shared__ int hist[NBUK_MAX];
    __shared__ int start[NBUK_MAX];
    __shared__ int adjs[NBUK_MAX];
    __shared__ int partial[512];
    __shared__ unsigned int stage_rec[CHUNK];
    __shared__ unsigned short stage_b[CHUNK];

    const int t = threadIdx.x;
    const int base = blockIdx.x * CHUNK;
    int n = E - base; if (n > CHUNK) n = CHUNK;

    hist[t] = 0; hist[t + 512] = 0;
    __syncthreads();

    unsigned int rec[8]; int bk[8]; int lr[8];
    #pragma unroll
    for (int k = 0; k < 8; ++k) {
        int i = t + k * 512;
        if (i < n) {
            int j = base + i;
            int d = dst_idx[j];
            int s = src_idx[j];
            int f = e_feat[j];
            bk[k]  = d >> LOGB;
            rec[k] = (unsigned)s | ((unsigned)(d & (NPB - 1)) << 17)
                                 | ((unsigned)f << 24);
            lr[k]  = atomicAdd(&hist[bk[k]], 1);
        } else bk[k] = -1;
    }
    __syncthreads();

    // exclusive scan of hist[0..1024) (2 buckets/thread)
    int a  = hist[2 * t];
    int b2 = hist[2 * t + 1];
    partial[t] = a + b2;
    __syncthreads();
    for (int off = 1; off < 512; off <<= 1) {
        int v = (t >= off) ? partial[t - off] : 0;
        __syncthreads();
        partial[t] += v;
        __syncthreads();
    }
    int pbase = partial[t] - (a + b2);
    start[2 * t]     = pbase;
    start[2 * t + 1] = pbase + a;
    __syncthreads();

    #pragma unroll
    for (int k = 0; k < 8; ++k) {
        if (bk[k] >= 0) {
            int pos = start[bk[k]] + lr[k];
            stage_rec[pos] = rec[k];
            stage_b[pos]   = (unsigned short)bk[k];
        }
    }
    for (int b = t; b < nbuk; b += 512) {
        int c = hist[b];
        if (c > 0) {
            int g0 = atomicAdd(&cursor[b], c);
            adjs[b] = g0 - start[b];
        }
    }
    __syncthreads();

    for (int i = t; i < n; i += 512) {
        int b  = stage_b[i];
        int dp = adjs[b] + i;
        unsigned int r = stage_rec[i];
        if (dp < CAP) {
            recs[(size_t)b * CAP + dp] = r;
        } else {
            int oi = atomicAdd(ovf_cnt, 1);
            if (oi < OVF_CAP) {
                int s  = r & 0x1FFFF;
                int dl = (r >> 17) & (NPB - 1);
                int f  = (r >> 24) & 7;
                ovf[oi] = make_int4((b << LOGB) | dl, s, f, 0);
            }
        }
    }
}

// ---------------- pass B: per-bucket node-sort + meta ----------------
__global__ __launch_bounds__(256) void k_regroup(
    const int* __restrict__ cursor, const unsigned int* __restrict__ recs,
    const float* __restrict__ sw,
    int2* __restrict__ recs2, int2* __restrict__ meta, int N)
{
    __shared__ int hist2[NPB];
    __shared__ int sc[NPB];
    __shared__ int nstart[NPB];
    __shared__ int2 rbuf[CAP];               // 16 KB

    const int t = threadIdx.x;
    const int b = blockIdx.x;
    int cnt = cursor[b]; if (cnt > CAP) cnt = CAP;

    for (int i = t; i < NPB; i += 256) hist2[i] = 0;
    __syncthreads();

    float s0 = sw[0], s1 = sw[1], s2 = sw[2], s3 = sw[3], s4 = sw[4];

    unsigned int r[8]; int nl[8]; int lr[8];
    #pragma unroll
    for (int k = 0; k < 8; ++k) {
        int i = t + k * 256;
        if (i < cnt) {
            r[k]  = recs[(size_t)b * CAP + i];
            nl[k] = (r[k] >> 17) & (NPB - 1);
            lr[k] = atomicAdd(&hist2[nl[k]], 1);
        } else nl[k] = -1;
    }
    __syncthreads();

    // exclusive scan of hist2[0..128) using first 128 threads
    if (t < NPB) sc[t] = hist2[t];
    __syncthreads();
    for (int off = 1; off < NPB; off <<= 1) {
        int v = (t < NPB && t >= off) ? sc[t - off] : 0;
        __syncthreads();
        if (t < NPB) sc[t] += v;
        __syncthreads();
    }
    if (t < NPB) nstart[t] = sc[t] - hist2[t];
    __syncthreads();

    #pragma unroll
    for (int k = 0; k < 8; ++k) {
        if (nl[k] >= 0) {
            int f = (r[k] >> 24) & 7;
            float c = s0;
            c += (f == 0) ? s1 : 0.0f;
            c += (f == 2) ? s2 : 0.0f;
            c += (f == 4) ? s3 : 0.0f;
            c += (f == 6) ? s4 : 0.0f;
            rbuf[nstart[nl[k]] + lr[k]] = make_int2((int)(r[k] & 0x1FFFF),
                                                    __float_as_int(c));
        }
    }
    __syncthreads();

    for (int i = t; i < cnt; i += 256)
        recs2[(size_t)b * CAP + i] = rbuf[i];

    const int node0 = b << LOGB;
    if (t < NPB) {
        int node = node0 + t;
        if (node < N)
            meta[node] = make_int2(b * CAP + nstart[t], hist2[t]);
    }
}

// ---------------- pass C: wave-per-node gather (R4-proven) ----------------
__global__ __launch_bounds__(256) void k_gather(
    const float* __restrict__ emb, const float* __restrict__ weight,
    const int2* __restrict__ meta, const int2* __restrict__ recs2,
    float* __restrict__ out, int N)
{
    int wave = threadIdx.x >> 6;
    int lane = threadIdx.x & 63;
    int node = blockIdx.x * 4 + wave;
    if (node >= N) return;

    int2 m = meta[node];
    int s = m.x, cnt = m.y;

    float a0=0.f,a1=0.f,a2=0.f,a3=0.f,a4=0.f,a5=0.f,a6=0.f,a7=0.f;

    for (int base = 0; base < cnt; base += 64) {
        int nch = cnt - base; if (nch > 64) nch = 64;
        int2 r = make_int2(0, 0);
        if (lane < nch) r = recs2[s + base + lane];
        int j = 0;
        for (; j + 7 < nch; j += 8) {
            int   s0 = __shfl(r.x, j    ), s1 = __shfl(r.x, j + 1);
            int   s2 = __shfl(r.x, j + 2), s3 = __shfl(r.x, j + 3);
            int   s4 = __shfl(r.x, j + 4), s5 = __shfl(r.x, j + 5);
            int   s6 = __shfl(r.x, j + 6), s7 = __shfl(r.x, j + 7);
            float c0 = __int_as_float(__shfl(r.y, j    ));
            float c1 = __int_as_float(__shfl(r.y, j + 1));
            float c2 = __int_as_float(__shfl(r.y, j + 2));
            float c3 = __int_as_float(__shfl(r.y, j + 3));
            float c4 = __int_as_float(__shfl(r.y, j + 4));
            float c5 = __int_as_float(__shfl(r.y, j + 5));
            float c6 = __int_as_float(__shfl(r.y, j + 6));
            float c7 = __int_as_float(__shfl(r.y, j + 7));
            a0 = fmaf(c0, emb[(size_t)s0 * DIM + lane], a0);
            a1 = fmaf(c1, emb[(size_t)s1 * DIM + lane], a1);
            a2 = fmaf(c2, emb[(size_t)s2 * DIM + lane], a2);
            a3 = fmaf(c3, emb[(size_t)s3 * DIM + lane], a3);
            a4 = fmaf(c4, emb[(size_t)s4 * DIM + lane], a4);
            a5 = fmaf(c5, emb[(size_t)s5 * DIM + lane], a5);
            a6 = fmaf(c6, emb[(size_t)s6 * DIM + lane], a6);
            a7 = fmaf(c7, emb[(size_t)s7 * DIM + lane], a7);
        }
        for (; j < nch; ++j) {
            int   sj = __shfl(r.x, j);
            float cj = __int_as_float(__shfl(r.y, j));
            a0 = fmaf(cj, emb[(size_t)sj * DIM + lane], a0);
        }
    }
    float acc = ((a0 + a1) + (a2 + a3)) + ((a4 + a5) + (a6 + a7));
    out[(size_t)node * DIM + lane] = acc * weight[lane];
}

// ---------------- pass D: overflow fixup (normally zero work) ----------------
__global__ __launch_bounds__(64) void k_overflow(
    const int* __restrict__ ovf_cnt, const int4* __restrict__ ovf,
    const float* __restrict__ emb, const float* __restrict__ weight,
    const float* __restrict__ sw, float* __restrict__ out)
{
    int m = *ovf_cnt; if (m > OVF_CAP) m = OVF_CAP;
    int lane = threadIdx.x;
    float s0 = sw[0], s1 = sw[1], s2 = sw[2], s3 = sw[3], s4 = sw[4];
    for (int i = blockIdx.x; i < m; i += gridDim.x) {
        int4 rec = ovf[i];
        int f = rec.z;
        float c = s0;
        c += (f == 0) ? s1 : 0.0f;
        c += (f == 2) ? s2 : 0.0f;
        c += (f == 4) ? s3 : 0.0f;
        c += (f == 6) ? s4 : 0.0f;
        float v = emb[(size_t)rec.y * DIM + lane] * weight[lane] * c;
        atomicAdd(&out[(size_t)rec.x * DIM + lane], v);
    }
}

// ---------------- fallback (tiny ws): round-1 atomic kernel ----------------
__global__ __launch_bounds__(256) void edge_scatter_kernel(
    const float* __restrict__ emb, const int* __restrict__ e_feat,
    const int* __restrict__ src_idx, const int* __restrict__ dst_idx,
    const float* __restrict__ weight, const float* __restrict__ sw,
    float* __restrict__ out, int n_edges) {
    int tid = blockIdx.x * blockDim.x + threadIdx.x;
    int edge = tid >> 4;
    int quad = tid & 15;
    if (edge >= n_edges) return;
    int ef = e_feat[edge];
    float coef = sw[0];
    coef += (ef == 0) ? sw[1] : 0.0f;
    coef += (ef == 2) ? sw[2] : 0.0f;
    coef += (ef == 4) ? sw[3] : 0.0f;
    coef += (ef == 6) ? sw[4] : 0.0f;
    int src = src_idx[edge], dst = dst_idx[edge];
    const float4 ev = *reinterpret_cast<const float4*>(emb + (size_t)src * DIM + quad * 4);
    const float4 wv = *reinterpret_cast<const float4*>(weight + quad * 4);
    float* op = out + (size_t)dst * DIM + quad * 4;
    atomicAdd(op + 0, ev.x * wv.x * coef);
    atomicAdd(op + 1, ev.y * wv.y * coef);
    atomicAdd(op + 2, ev.z * wv.z * coef);
    atomicAdd(op + 3, ev.w * wv.w * coef);
}

extern "C" void kernel_launch(void* const* d_in, const int* in_sizes, int n_in,
                              void* d_out, int out_size, void* d_ws, size_t ws_size,
                              hipStream_t stream) {
    const float* emb     = (const float*)d_in[0];
    const int*   e_feat  = (const int*)d_in[1];
    const int*   src_idx = (const int*)d_in[2];
    const int*   dst_idx = (const int*)d_in[3];
    const float* weight  = (const float*)d_in[4];
    const float* sw      = (const float*)d_in[5];
    float* out = (float*)d_out;

    const int E = in_sizes[1];
    const int N = in_sizes[0] / DIM;
    const int nbuk = (N + NPB - 1) / NPB;    // 782 for N=100000

    // ws: cursor[nbuk] | ovf_cnt | ovf[OVF_CAP] | recs[nbuk*CAP] u32
    //     | recs2[nbuk*CAP] int2 | meta[N] int2
    size_t off_cursor = 0;
    size_t off_ovfcnt = off_cursor + (size_t)nbuk * 4;
    size_t off_ovf    = (off_ovfcnt + 4 + 15) & ~(size_t)15;
    size_t off_recs   = (off_ovf + (size_t)OVF_CAP * 16 + 15) & ~(size_t)15;
    size_t off_recs2  = (off_recs + (size_t)nbuk * CAP * 4 + 15) & ~(size_t)15;
    size_t off_meta   = (off_recs2 + (size_t)nbuk * CAP * 8 + 15) & ~(size_t)15;
    size_t needed     = off_meta + (size_t)N * 8;

    if (nbuk > NBUK_MAX || ws_size < needed) {
        hipMemsetAsync(d_out, 0, (size_t)out_size * sizeof(float), stream);
        int total = E * 16, block = 256;
        edge_scatter_kernel<<<(total + block - 1) / block, block, 0, stream>>>(
            emb, e_feat, src_idx, dst_idx, weight, sw, out, E);
        return;
    }

    char* ws = (char*)d_ws;
    int*          cursor  = (int*)(ws + off_cursor);
    int*          ovf_cnt = (int*)(ws + off_ovfcnt);
    int4*         ovf     = (int4*)(ws + off_ovf);
    unsigned int* recs    = (unsigned int*)(ws + off_recs);
    int2*         recs2   = (int2*)(ws + off_recs2);
    int2*         meta    = (int2*)(ws + off_meta);

    hipMemsetAsync(cursor, 0, off_ovfcnt + 16 - off_cursor, stream);

    k_bin<<<(E + CHUNK - 1) / CHUNK, 512, 0, stream>>>(
        e_feat, src_idx, dst_idx, cursor, ovf_cnt, ovf, recs, E, nbuk);

    k_regroup<<<nbuk, 256, 0, stream>>>(cursor, recs, sw, recs2, meta, N);

    k_gather<<<(N + 3) / 4, 256, 0, stream>>>(emb, weight, meta, recs2, out, N);

    k_overflow<<<64, 64, 0, stream>>>(ovf_cnt, ovf, emb, weight, sw, out);
}